// Round 9
// baseline (10278.415 us; speedup 1.0000x reference)
//
#include <hip/hip_runtime.h>

// Persistent 3-layer tanh-RNN, B=32, S=1024, I=128, H=512.
// f16 split-2 (hi + lo*2^-12) x 3 MFMA products == fp32-class precision.
// 96 blocks = 3 layers x 16 j-groups(32 j) x 2 b-groups(16 b); weights live in
// VGPRs as MFMA B-frags for the whole kernel.
//
// R9: shorten the serial segment inside the R6 skeleton (6630us best).
// Sync primitives unchanged (agent byte/dword flags, ballot poll, acquire
// fence, plain cached data loads, sc1 agent stores, release flag store):
//   1. TWO-PHASE step: poll upstream(t) -> fence -> input-half load+MFMA
//      (accumulates in registers), THEN poll own(t-1) -> fence -> rec-half.
//      K-tiles re-interleaved so each wave holds 4 input + 4 rec tiles
//      (L0: 1+4) -> only the rec half rides the recurrent critical path.
//   2. ALL waves poll in parallel (each checks all 16 producer dwords);
//      one barrier per step, double-buffered LDS reduce (WAR-safe).
//   3. DISTRIBUTED epilogue: every wave publishes P to LDS; each wave
//      reduces + tanh + stores only its r=w quarter (2 stores), drains its
//      own stores and sets ITS byte of the per-block flag dword.
//   Flags: dword per (c=(L,bg), jg) x (t&255) ring, byte value = epoch
//   (t>>8)+1 -> 96KB in d_out's dead region, no clearing, launch-memset.
// Lessons kept: no agent atomic data loads (R5/R8), no placement
// assumptions (R3/R4), 96-block geometry (R7). Polls timeout-bounded.

typedef _Float16 half8 __attribute__((ext_vector_type(8)));
typedef float f32x4 __attribute__((ext_vector_type(4)));
typedef unsigned int uint32;
typedef unsigned short ushort16;

#define SCOPE_AGENT __HIP_MEMORY_SCOPE_AGENT
#define PLANE_ELEMS (32 * 1024 * 512)
#define FLAG_BYTES (6 * 16 * 256 * 4)  // [c][jg][t&255] dwords (byte per wave) = 96 KB < 128 KB

__device__ __forceinline__ half8 h8(uint32 a, uint32 b, uint32 c, uint32 d) {
  union { uint32 u[4]; half8 h; } x;
  x.u[0] = a; x.u[1] = b; x.u[2] = c; x.u[3] = d;
  return x.h;
}

// pair dword: low16 = hi-f16 bits, high16 = lo-f16 bits
__device__ __forceinline__ void unpack_pair8(uint4 a, uint4 b, half8& hi, half8& lo) {
  hi = h8((a.x & 0xFFFFu) | (a.y << 16),
          (a.z & 0xFFFFu) | (a.w << 16),
          (b.x & 0xFFFFu) | (b.y << 16),
          (b.z & 0xFFFFu) | (b.w << 16));
  lo = h8((a.x >> 16) | (a.y & 0xFFFF0000u),
          (a.z >> 16) | (a.w & 0xFFFF0000u),
          (b.x >> 16) | (b.y & 0xFFFF0000u),
          (b.z >> 16) | (b.w & 0xFFFF0000u));
}

__device__ __forceinline__ void split8f(const float* v, half8& hi, half8& lo) {
  union { _Float16 e[8]; half8 h; } H, L;
#pragma unroll
  for (int i = 0; i < 8; ++i) {
    _Float16 h = (_Float16)v[i];
    H.e[i] = h;
    L.e[i] = (_Float16)((v[i] - (float)h) * 4096.0f);  // exact residual, scaled into f16 normal range
  }
  hi = H.h; lo = L.h;
}

__device__ __forceinline__ uint32 pack_pair(float xx) {
  _Float16 h = (_Float16)xx;
  _Float16 l = (_Float16)((xx - (float)h) * 4096.0f);
  union { _Float16 f; ushort16 u; } ch, cl;
  ch.f = h; cl.f = l;
  return (uint32)ch.u | ((uint32)cl.u << 16);
}

__device__ __forceinline__ void frag_from_f32(const float* p, half8& hi, half8& lo) {
  float v[8];
  *(float4*)(v)     = *(const float4*)(p);
  *(float4*)(v + 4) = *(const float4*)(p + 4);
  split8f(v, hi, lo);
}

__device__ __forceinline__ void frag_from_pairs(const uint32* p, half8& hi, half8& lo) {
  uint4 a = *(const uint4*)p;
  uint4 b = *(const uint4*)(p + 4);
  unpack_pair8(a, b, hi, lo);
}

template <int L>
__device__ void run_layer(const float* __restrict__ x, const float* __restrict__ h0,
                          const float* __restrict__ w_ih0, const float* __restrict__ w_ihs,
                          const float* __restrict__ w_hhs, const float* __restrict__ b_ihs,
                          const float* __restrict__ b_hhs, uint32* __restrict__ plane0,
                          uint32* __restrict__ plane1, float* __restrict__ outp, int jg, int bg) {
  constexpr int IN_PW = (L == 0) ? 1 : 4;   // input k-tiles per wave (interleaved: ti = w or w*4+i)
  constexpr int REC_PW = 4;                 // rec k-tiles per wave (tr = w*4+i)

  unsigned char* flagb = (unsigned char*)outp;
  uint32* flag32 = (uint32*)outp;
  float* hidden = outp;
  float* out2 = outp + 3 * 32 * 512;

  const int tid = threadIdx.x;
  const int w = tid >> 6;
  const int lane = tid & 63;
  const int ln16 = lane & 15;
  const int kgrp = lane >> 4;               // frag k-group: k8 = kgrp*8
  const int j0 = jg * 32;
  const int jc0 = j0 + ln16;                // jtile-0 column for this lane
  const int jc1 = j0 + 16 + ln16;           // jtile-1 column
  const int bloc = bg * 16 + ln16;          // A-frag row (batch)
  const int c = L * 2 + bg;                 // producer group id
  const int uc = (L - 1) * 2 + bg;          // upstream group id (L>0)

  __shared__ f32x4 red[2][8][64];           // [t&1][w*2+jt][lane] — double-buffered, 16 KB
  __shared__ int s_abort;
  if (tid == 0) s_abort = 0;

  // ---- preload weights (step-invariant) into VGPRs as hi/lo B-frags ----
  half8 Bih[2][IN_PW], Bil[2][IN_PW], Brh[2][REC_PW], Brl[2][REC_PW];
#pragma unroll
  for (int jt = 0; jt < 2; ++jt) {
    const int j = j0 + jt * 16 + ln16;
#pragma unroll
    for (int i = 0; i < IN_PW; ++i) {
      const int ti = (L == 0) ? w : (w * 4 + i);
      const float* wp = (L == 0) ? (w_ih0 + j * 128 + ti * 32 + kgrp * 8)
                                 : (w_ihs + (L - 1) * 512 * 512 + j * 512 + ti * 32 + kgrp * 8);
      frag_from_f32(wp, Bih[jt][i], Bil[jt][i]);
    }
#pragma unroll
    for (int i = 0; i < REC_PW; ++i) {
      const int tr = w * 4 + i;
      frag_from_f32(w_hhs + L * 512 * 512 + j * 512 + tr * 32 + kgrp * 8, Brh[jt][i], Brl[jt][i]);
    }
  }

  const float bias0 = b_ihs[L * 512 + jc0] + b_hhs[L * 512 + jc0];
  const float bias1 = b_ihs[L * 512 + jc1] + b_hhs[L * 512 + jc1];
  uint32* myplane = (L == 0) ? plane0 : plane1;        // L==2 never uses it
  const uint32* plane_in = (L == 1) ? plane0 : plane1; // cross-layer input source (L>0)
  __syncthreads();

  for (int t = 0; t < 1024; ++t) {
    f32x4 C0 = {0.f, 0.f, 0.f, 0.f}, C1 = C0, X0 = C0, X1 = C0;

    // ================= PHASE A: input half (off the rec critical path) ===========
    if (L > 0) {
      // poll upstream(t): 16 producer dwords, one per lane
      const uint32* pp = (lane < 16) ? (flag32 + ((uc * 16 + lane) << 8) + (t & 255)) : nullptr;
      const uint32 pat = 0x01010101u * (uint32)((t >> 8) + 1);
      int spins = 0;
      for (;;) {
        bool ready = true;
        if (pp) ready = (__hip_atomic_load(pp, __ATOMIC_RELAXED, SCOPE_AGENT) == pat);
        if (__ballot(ready) == ~0ull) break;
        if (++spins > 250000) { s_abort = 1; break; }  // bounded -> degrade, never hang
        if (spins > 64) __builtin_amdgcn_s_sleep(1);
      }
      __builtin_amdgcn_fence(__ATOMIC_ACQUIRE, "agent");
    }
    {
      const uint32* inP = (L > 0) ? (plane_in + (t * 32 + bloc) * 512) : nullptr;
      const float* inF = (L == 0) ? (x + (bloc * 1024 + t) * 128) : nullptr;
#pragma unroll
      for (int i = 0; i < IN_PW; ++i) {
        const int ti = (L == 0) ? w : (w * 4 + i);
        const int k = ti * 32 + kgrp * 8;
        half8 Ahi, Alo;
        if (L == 0) frag_from_f32(inF + k, Ahi, Alo);
        else        frag_from_pairs(inP + k, Ahi, Alo);
        C0 = __builtin_amdgcn_mfma_f32_16x16x32_f16(Ahi, Bih[0][i], C0, 0, 0, 0);
        C1 = __builtin_amdgcn_mfma_f32_16x16x32_f16(Ahi, Bih[1][i], C1, 0, 0, 0);
        X0 = __builtin_amdgcn_mfma_f32_16x16x32_f16(Ahi, Bil[0][i], X0, 0, 0, 0);
        X1 = __builtin_amdgcn_mfma_f32_16x16x32_f16(Ahi, Bil[1][i], X1, 0, 0, 0);
        X0 = __builtin_amdgcn_mfma_f32_16x16x32_f16(Alo, Bih[0][i], X0, 0, 0, 0);
        X1 = __builtin_amdgcn_mfma_f32_16x16x32_f16(Alo, Bih[1][i], X1, 0, 0, 0);
      }
    }

    // ================= PHASE B: recurrent half (the serial chain) ================
    if (t > 0) {
      // poll own-layer(t-1): 16 producer dwords (incl. own block, set last step)
      const uint32* pp = (lane < 16) ? (flag32 + ((c * 16 + lane) << 8) + ((t - 1) & 255)) : nullptr;
      const uint32 pat = 0x01010101u * (uint32)(((t - 1) >> 8) + 1);
      int spins = 0;
      for (;;) {
        bool ready = true;
        if (pp) ready = (__hip_atomic_load(pp, __ATOMIC_RELAXED, SCOPE_AGENT) == pat);
        if (__ballot(ready) == ~0ull) break;
        if (++spins > 250000) { s_abort = 1; break; }
        if (spins > 64) __builtin_amdgcn_s_sleep(1);
      }
      __builtin_amdgcn_fence(__ATOMIC_ACQUIRE, "agent");  // phase-A results live in registers
    }
    {
      const float* recF = nullptr; const uint32* recP = nullptr;
      if (t == 0)      recF = h0 + (L * 32 + bloc) * 512;
      else if (L == 2) recF = out2 + (bloc * 1024 + (t - 1)) * 512;
      else             recP = myplane + ((t - 1) * 32 + bloc) * 512;
#pragma unroll
      for (int i = 0; i < REC_PW; ++i) {
        const int k = (w * 4 + i) * 32 + kgrp * 8;
        half8 Ahi, Alo;
        if (t == 0 || L == 2) frag_from_f32(recF + k, Ahi, Alo);
        else                  frag_from_pairs(recP + k, Ahi, Alo);
        C0 = __builtin_amdgcn_mfma_f32_16x16x32_f16(Ahi, Brh[0][i], C0, 0, 0, 0);
        C1 = __builtin_amdgcn_mfma_f32_16x16x32_f16(Ahi, Brh[1][i], C1, 0, 0, 0);
        X0 = __builtin_amdgcn_mfma_f32_16x16x32_f16(Ahi, Brl[0][i], X0, 0, 0, 0);
        X1 = __builtin_amdgcn_mfma_f32_16x16x32_f16(Ahi, Brl[1][i], X1, 0, 0, 0);
        X0 = __builtin_amdgcn_mfma_f32_16x16x32_f16(Alo, Brh[0][i], X0, 0, 0, 0);
        X1 = __builtin_amdgcn_mfma_f32_16x16x32_f16(Alo, Brh[1][i], X1, 0, 0, 0);
      }
    }

    f32x4 P0 = C0 + X0 * (1.0f / 4096.0f);
    f32x4 P1 = C1 + X1 * (1.0f / 4096.0f);

    const int p = t & 1;
    red[p][w * 2 + 0][lane] = P0;
    red[p][w * 2 + 1][lane] = P1;
    __syncthreads();               // the ONLY barrier per step (red double-buffered)
    if (s_abort) break;

    // ---- distributed epilogue: wave w handles r = w (rows kgrp*4 + w) ----
    float s0 = 0.f, s1 = 0.f;
#pragma unroll
    for (int wv = 0; wv < 4; ++wv) {
      s0 += ((const float*)&red[p][wv * 2 + 0][lane])[w];
      s1 += ((const float*)&red[p][wv * 2 + 1][lane])[w];
    }
    const float y0 = tanhf(s0 + bias0);
    const float y1 = tanhf(s1 + bias1);
    const int b = bg * 16 + kgrp * 4 + w;
    if (L < 2) {
      __hip_atomic_store(&myplane[(t * 32 + b) * 512 + jc0], pack_pair(y0), __ATOMIC_RELAXED, SCOPE_AGENT);
      __hip_atomic_store(&myplane[(t * 32 + b) * 512 + jc1], pack_pair(y1), __ATOMIC_RELAXED, SCOPE_AGENT);
    } else {
      __hip_atomic_store(&out2[(b * 1024 + t) * 512 + jc0], y0, __ATOMIC_RELAXED, SCOPE_AGENT);
      __hip_atomic_store(&out2[(b * 1024 + t) * 512 + jc1], y1, __ATOMIC_RELAXED, SCOPE_AGENT);
      if (t == 1023) {
        hidden[2 * 32 * 512 + b * 512 + jc0] = y0;
        hidden[2 * 32 * 512 + b * 512 + jc1] = y1;
      }
    }
    // per-WAVE release byte (epoch value): drains only THIS wave's stores
    if (lane == 0)
      __hip_atomic_store(flagb + ((((c * 16 + jg) << 8) + (t & 255)) << 2) + w,
                         (unsigned char)((t >> 8) + 1), __ATOMIC_RELEASE, SCOPE_AGENT);
  }
}

__global__ __launch_bounds__(256) void rnn_persist(
    const float* __restrict__ x, const float* __restrict__ h0,
    const float* __restrict__ w_ih0, const float* __restrict__ w_ihs,
    const float* __restrict__ w_hhs, const float* __restrict__ b_ihs,
    const float* __restrict__ b_hhs, uint32* __restrict__ plane0,
    uint32* __restrict__ plane1, float* __restrict__ outp) {
  const int bid = blockIdx.x;
  const int l = bid >> 5;
  const int idx = bid & 31;
  const int jg = idx >> 1;
  const int bg = idx & 1;
  if (l == 0)      run_layer<0>(x, h0, w_ih0, w_ihs, w_hhs, b_ihs, b_hhs, plane0, plane1, outp, jg, bg);
  else if (l == 1) run_layer<1>(x, h0, w_ih0, w_ihs, w_hhs, b_ihs, b_hhs, plane0, plane1, outp, jg, bg);
  else             run_layer<2>(x, h0, w_ih0, w_ihs, w_hhs, b_ihs, b_hhs, plane0, plane1, outp, jg, bg);
}

// hidden[l][b][j] for l in {0,1} from the last pair-plane slot (exact-ish: hi + lo*2^-12)
__global__ __launch_bounds__(256) void finals_kernel(const uint32* __restrict__ plane0,
                                                     const uint32* __restrict__ plane1,
                                                     float* __restrict__ outp) {
  int i = blockIdx.x * 256 + threadIdx.x;
  if (i >= 2 * 32 * 512) return;
  int l = i >> 14;
  int r = i & 16383;  // b*512 + j
  const uint32* pl = l ? plane1 : plane0;
  uint32 p = pl[1023 * 32 * 512 + r];
  union { ushort16 u; _Float16 f; } h, lo;
  h.u = (ushort16)(p & 0xFFFFu);
  lo.u = (ushort16)(p >> 16);
  outp[i] = (float)h.f + (float)lo.f * (1.0f / 4096.0f);
}

extern "C" void kernel_launch(void* const* d_in, const int* in_sizes, int n_in,
                              void* d_out, int out_size, void* d_ws, size_t ws_size,
                              hipStream_t stream) {
  const float* x     = (const float*)d_in[0];
  const float* h0    = (const float*)d_in[1];
  const float* w_ih0 = (const float*)d_in[2];
  const float* w_ihs = (const float*)d_in[3];
  const float* w_hhs = (const float*)d_in[4];
  const float* b_ihs = (const float*)d_in[5];
  const float* b_hhs = (const float*)d_in[6];

  uint32* plane0 = (uint32*)d_ws;            // layer-0 outputs, (hi,lo) f16 pairs, 64 MB
  uint32* plane1 = plane0 + PLANE_ELEMS;     // layer-1 outputs, 64 MB

  // zero the flag dwords (dead hidden region of d_out, below hidden[2] at
  // 128 KB; rewritten by finals_kernel at the end)
  hipMemsetAsync(d_out, 0, FLAG_BYTES, stream);
  rnn_persist<<<96, 256, 0, stream>>>(x, h0, w_ih0, w_ihs, w_hhs, b_ihs, b_hhs,
                                      plane0, plane1, (float*)d_out);
  finals_kernel<<<128, 256, 0, stream>>>(plane0, plane1, (float*)d_out);
}

// Round 10
// 9635.667 us; speedup vs baseline: 1.0667x; 1.0667x over previous
//
#include <hip/hip_runtime.h>

// Persistent 3-layer tanh-RNN, B=32, S=1024, I=128, H=512.
// f16 split-2 (hi + lo*2^-12) x 3 MFMA products == fp32-class precision.
// 96 blocks = 3 layers x 16 j-groups(32 j) x 2 b-groups(16 b); weights live in
// VGPRs as MFMA B-frags for the whole kernel.
//
// R10 = R6 skeleton (best verified, 6630us: single fused wave-0 poll, one
// acquire fence, plain cached in-loop frag loads, one barrier) + ONE delta:
// DISTRIBUTED EPILOGUE. All 4 waves write P to LDS in a conflict-free
// layout red[wv][jt][r][lane] (lane-stride-1 floats; R9's scalar reads were
// an 8-way bank conflict); after the barrier wave w reduces rows r=w only:
// 2 tanh + 2 stores + its own drain + its own release byte (byte w of the
// per-block epoch dword -- R9's flag scheme, correctness-proven there).
// Epilogue parallelism 4x; wave 0 reaches the next poll earlier.
// Lessons kept: ONE poll + ONE fence + ONE barrier per step (R9), no agent
// atomic data loads (R5/R8), no placement assumptions (R3/R4), 96-block
// geometry (R7). Polls timeout-bounded (degrade, never hang).

typedef _Float16 half8 __attribute__((ext_vector_type(8)));
typedef float f32x4 __attribute__((ext_vector_type(4)));
typedef unsigned int uint32;
typedef unsigned short ushort16;

#define SCOPE_AGENT __HIP_MEMORY_SCOPE_AGENT
#define PLANE_ELEMS (32 * 1024 * 512)
#define FLAG_BYTES (6 * 16 * 256 * 4)  // [c=(L,bg)][jg][t&255] epoch dwords (byte per wave) = 96 KB

__device__ __forceinline__ half8 h8(uint32 a, uint32 b, uint32 c, uint32 d) {
  union { uint32 u[4]; half8 h; } x;
  x.u[0] = a; x.u[1] = b; x.u[2] = c; x.u[3] = d;
  return x.h;
}

// pair dword: low16 = hi-f16 bits, high16 = lo-f16 bits
__device__ __forceinline__ void unpack_pair8(uint4 a, uint4 b, half8& hi, half8& lo) {
  hi = h8((a.x & 0xFFFFu) | (a.y << 16),
          (a.z & 0xFFFFu) | (a.w << 16),
          (b.x & 0xFFFFu) | (b.y << 16),
          (b.z & 0xFFFFu) | (b.w << 16));
  lo = h8((a.x >> 16) | (a.y & 0xFFFF0000u),
          (a.z >> 16) | (a.w & 0xFFFF0000u),
          (b.x >> 16) | (b.y & 0xFFFF0000u),
          (b.z >> 16) | (b.w & 0xFFFF0000u));
}

__device__ __forceinline__ void split8f(const float* v, half8& hi, half8& lo) {
  union { _Float16 e[8]; half8 h; } H, L;
#pragma unroll
  for (int i = 0; i < 8; ++i) {
    _Float16 h = (_Float16)v[i];
    H.e[i] = h;
    L.e[i] = (_Float16)((v[i] - (float)h) * 4096.0f);  // exact residual, scaled into f16 normal range
  }
  hi = H.h; lo = L.h;
}

__device__ __forceinline__ uint32 pack_pair(float xx) {
  _Float16 h = (_Float16)xx;
  _Float16 l = (_Float16)((xx - (float)h) * 4096.0f);
  union { _Float16 f; ushort16 u; } ch, cl;
  ch.f = h; cl.f = l;
  return (uint32)ch.u | ((uint32)cl.u << 16);
}

__device__ __forceinline__ void frag_from_f32(const float* p, half8& hi, half8& lo) {
  float v[8];
  *(float4*)(v)     = *(const float4*)(p);
  *(float4*)(v + 4) = *(const float4*)(p + 4);
  split8f(v, hi, lo);
}

__device__ __forceinline__ void frag_from_pairs(const uint32* p, half8& hi, half8& lo) {
  uint4 a = *(const uint4*)p;
  uint4 b = *(const uint4*)(p + 4);
  unpack_pair8(a, b, hi, lo);
}

template <int L>
__device__ void run_layer(const float* __restrict__ x, const float* __restrict__ h0,
                          const float* __restrict__ w_ih0, const float* __restrict__ w_ihs,
                          const float* __restrict__ w_hhs, const float* __restrict__ b_ihs,
                          const float* __restrict__ b_hhs, uint32* __restrict__ plane0,
                          uint32* __restrict__ plane1, float* __restrict__ outp, int jg, int bg) {
  constexpr int NKT = (L == 0) ? 20 : 32;   // K-tiles of 32 (l0: 4 x-tiles + 16 rec; else 16 in + 16 rec)
  constexpr int KTN = NKT / 4;              // tiles per wave
  constexpr int RECKT = (L == 0) ? 4 : 16;  // first recurrent tile

  unsigned char* flagb = (unsigned char*)outp;
  uint32* flag32 = (uint32*)outp;
  float* hidden = outp;
  float* out2 = outp + 3 * 32 * 512;

  const int tid = threadIdx.x;
  const int w = tid >> 6;
  const int lane = tid & 63;
  const int ln16 = lane & 15;
  const int kgrp = lane >> 4;               // frag k-group: k8 = kgrp*8
  const int j0 = jg * 32;
  const int jc0 = j0 + ln16;                // jtile-0 column for this lane
  const int jc1 = j0 + 16 + ln16;           // jtile-1 column
  const int bloc = bg * 16 + ln16;          // A-frag row (batch)
  const int ktb = w * KTN;
  const int c = L * 2 + bg;                 // producer group id
  const int uc = (L - 1) * 2 + bg;          // upstream group id (L>0)

  __shared__ float red[4][2][4][64];        // [wv][jt][r][lane] — lane-stride-1, conflict-free
  __shared__ int s_abort;
  if (tid == 0) s_abort = 0;

  // ---- preload weights (step-invariant) into VGPRs as hi/lo B-frags ----
  half8 Bhi[2][KTN], Blo[2][KTN];
#pragma unroll
  for (int jt = 0; jt < 2; ++jt) {
    const int j = j0 + jt * 16 + ln16;
#pragma unroll
    for (int ktl = 0; ktl < KTN; ++ktl) {
      const int kt = ktb + ktl;
      const float* wp;
      if (L == 0) {
        if (kt < 4) wp = w_ih0 + j * 128 + kt * 32 + kgrp * 8;
        else        wp = w_hhs + j * 512 + (kt - 4) * 32 + kgrp * 8;
      } else {
        if (kt < 16) wp = w_ihs + (L - 1) * 512 * 512 + j * 512 + kt * 32 + kgrp * 8;
        else         wp = w_hhs + L * 512 * 512 + j * 512 + (kt - 16) * 32 + kgrp * 8;
      }
      frag_from_f32(wp, Bhi[jt][ktl], Blo[jt][ktl]);
    }
  }

  const float bias0 = b_ihs[L * 512 + jc0] + b_hhs[L * 512 + jc0];
  const float bias1 = b_ihs[L * 512 + jc1] + b_hhs[L * 512 + jc1];
  uint32* myplane = (L == 0) ? plane0 : plane1;  // L==2 never uses it
  __syncthreads();

  for (int t = 0; t < 1024; ++t) {
    // ---- fused readiness poll: wave 0; lanes 0-15 own-layer(t-1), lanes 16-31 upstream(t) ----
    // One epoch dword per producer block; ready when dword == epoch*0x01010101
    // (all 4 of that block's waves released their stores).
    if (w == 0) {
      const uint32* pp = nullptr; uint32 pat = 0;
      if (lane < 16) {
        if (t > 0) { pp = flag32 + ((c * 16 + lane) << 8) + ((t - 1) & 255);
                     pat = 0x01010101u * (uint32)(((t - 1) >> 8) + 1); }
      } else if (lane < 32) {
        if (L > 0) { pp = flag32 + ((uc * 16 + (lane - 16)) << 8) + (t & 255);
                     pat = 0x01010101u * (uint32)((t >> 8) + 1); }
      }
      int spins = 0;
      for (;;) {
        bool ready = true;
        if (pp) ready = (__hip_atomic_load(pp, __ATOMIC_RELAXED, SCOPE_AGENT) == pat);
        if (__ballot(ready) == ~0ull) break;
        if (++spins > 250000) { if (lane == 0) s_abort = 1; break; }  // bounded -> degrade, never hang
        if (spins > 64) __builtin_amdgcn_s_sleep(1);
      }
      __builtin_amdgcn_fence(__ATOMIC_ACQUIRE, "agent");  // invalidate stale cached lines
    }
    __syncthreads();
    if (s_abort) break;

    // ---- per-step source row pointers ----
    const float* recF = nullptr; const uint32* recP = nullptr;
    if (t == 0)      recF = h0 + (L * 32 + bloc) * 512;
    else if (L < 2)  recP = myplane + ((t - 1) * 32 + bloc) * 512;
    else             recF = out2 + (bloc * 1024 + (t - 1)) * 512;

    const float* inF = nullptr; const uint32* inP = nullptr;
    if (L == 0)      inF = x + (bloc * 1024 + t) * 128;
    else if (L == 1) inP = plane0 + (t * 32 + bloc) * 512;
    else             inP = plane1 + (t * 32 + bloc) * 512;

    f32x4 C0 = {0.f, 0.f, 0.f, 0.f}, C1 = C0, X0 = C0, X1 = C0;

#pragma unroll
    for (int ktl = 0; ktl < KTN; ++ktl) {
      const int kt = ktb + ktl;
      half8 Ahi, Alo;
      if (kt < RECKT) {  // input half
        const int k = kt * 32 + kgrp * 8;
        if (L == 0) frag_from_f32(inF + k, Ahi, Alo);
        else        frag_from_pairs(inP + k, Ahi, Alo);
      } else {           // recurrent half
        const int k = (kt - RECKT) * 32 + kgrp * 8;
        if (t == 0 || L == 2) frag_from_f32(recF + k, Ahi, Alo);
        else                  frag_from_pairs(recP + k, Ahi, Alo);
      }
      C0 = __builtin_amdgcn_mfma_f32_16x16x32_f16(Ahi, Bhi[0][ktl], C0, 0, 0, 0);
      C1 = __builtin_amdgcn_mfma_f32_16x16x32_f16(Ahi, Bhi[1][ktl], C1, 0, 0, 0);
      X0 = __builtin_amdgcn_mfma_f32_16x16x32_f16(Ahi, Blo[0][ktl], X0, 0, 0, 0);
      X1 = __builtin_amdgcn_mfma_f32_16x16x32_f16(Ahi, Blo[1][ktl], X1, 0, 0, 0);
      X0 = __builtin_amdgcn_mfma_f32_16x16x32_f16(Alo, Bhi[0][ktl], X0, 0, 0, 0);
      X1 = __builtin_amdgcn_mfma_f32_16x16x32_f16(Alo, Bhi[1][ktl], X1, 0, 0, 0);
    }

    f32x4 P0 = C0 + X0 * (1.0f / 4096.0f);
    f32x4 P1 = C1 + X1 * (1.0f / 4096.0f);

    // ---- all waves publish P (conflict-free layout) ----
#pragma unroll
    for (int r = 0; r < 4; ++r) {
      red[w][0][r][lane] = P0[r];
      red[w][1][r][lane] = P1[r];
    }
    __syncthreads();

    // ---- distributed epilogue: wave w handles rows r = w ----
    {
      float s0 = red[0][0][w][lane] + red[1][0][w][lane] + red[2][0][w][lane] + red[3][0][w][lane];
      float s1 = red[0][1][w][lane] + red[1][1][w][lane] + red[2][1][w][lane] + red[3][1][w][lane];
      const float y0 = tanhf(s0 + bias0);
      const float y1 = tanhf(s1 + bias1);
      const int b = bg * 16 + kgrp * 4 + w;  // C/D: col=lane&15, row=(lane>>4)*4+r, r==w
      if (L < 2) {
        __hip_atomic_store(&myplane[(t * 32 + b) * 512 + jc0], pack_pair(y0), __ATOMIC_RELAXED, SCOPE_AGENT);
        __hip_atomic_store(&myplane[(t * 32 + b) * 512 + jc1], pack_pair(y1), __ATOMIC_RELAXED, SCOPE_AGENT);
      } else {
        __hip_atomic_store(&out2[(b * 1024 + t) * 512 + jc0], y0, __ATOMIC_RELAXED, SCOPE_AGENT);
        __hip_atomic_store(&out2[(b * 1024 + t) * 512 + jc1], y1, __ATOMIC_RELAXED, SCOPE_AGENT);
        if (t == 1023) {
          hidden[2 * 32 * 512 + b * 512 + jc0] = y0;
          hidden[2 * 32 * 512 + b * 512 + jc1] = y1;
        }
      }
      // per-WAVE release byte (epoch value): drains THIS wave's stores only
      if (lane == 0)
        __hip_atomic_store(flagb + ((((c * 16 + jg) << 8) + (t & 255)) << 2) + w,
                           (unsigned char)((t >> 8) + 1), __ATOMIC_RELEASE, SCOPE_AGENT);
    }
    // no second barrier: red(t+1) writes happen only after the post-poll
    // __syncthreads() of step t+1, which every wave reaches after its
    // epilogue reads of red(t) -- WAR-safe with a single buffer.
  }
}

__global__ __launch_bounds__(256) void rnn_persist(
    const float* __restrict__ x, const float* __restrict__ h0,
    const float* __restrict__ w_ih0, const float* __restrict__ w_ihs,
    const float* __restrict__ w_hhs, const float* __restrict__ b_ihs,
    const float* __restrict__ b_hhs, uint32* __restrict__ plane0,
    uint32* __restrict__ plane1, float* __restrict__ outp) {
  const int bid = blockIdx.x;
  const int l = bid >> 5;
  const int idx = bid & 31;
  const int jg = idx >> 1;
  const int bg = idx & 1;
  if (l == 0)      run_layer<0>(x, h0, w_ih0, w_ihs, w_hhs, b_ihs, b_hhs, plane0, plane1, outp, jg, bg);
  else if (l == 1) run_layer<1>(x, h0, w_ih0, w_ihs, w_hhs, b_ihs, b_hhs, plane0, plane1, outp, jg, bg);
  else             run_layer<2>(x, h0, w_ih0, w_ihs, w_hhs, b_ihs, b_hhs, plane0, plane1, outp, jg, bg);
}

// hidden[l][b][j] for l in {0,1} from the last pair-plane slot (exact-ish: hi + lo*2^-12)
__global__ __launch_bounds__(256) void finals_kernel(const uint32* __restrict__ plane0,
                                                     const uint32* __restrict__ plane1,
                                                     float* __restrict__ outp) {
  int i = blockIdx.x * 256 + threadIdx.x;
  if (i >= 2 * 32 * 512) return;
  int l = i >> 14;
  int r = i & 16383;  // b*512 + j
  const uint32* pl = l ? plane1 : plane0;
  uint32 p = pl[1023 * 32 * 512 + r];
  union { ushort16 u; _Float16 f; } h, lo;
  h.u = (ushort16)(p & 0xFFFFu);
  lo.u = (ushort16)(p >> 16);
  outp[i] = (float)h.f + (float)lo.f * (1.0f / 4096.0f);
}

extern "C" void kernel_launch(void* const* d_in, const int* in_sizes, int n_in,
                              void* d_out, int out_size, void* d_ws, size_t ws_size,
                              hipStream_t stream) {
  const float* x     = (const float*)d_in[0];
  const float* h0    = (const float*)d_in[1];
  const float* w_ih0 = (const float*)d_in[2];
  const float* w_ihs = (const float*)d_in[3];
  const float* w_hhs = (const float*)d_in[4];
  const float* b_ihs = (const float*)d_in[5];
  const float* b_hhs = (const float*)d_in[6];

  uint32* plane0 = (uint32*)d_ws;            // layer-0 outputs, (hi,lo) f16 pairs, 64 MB
  uint32* plane1 = plane0 + PLANE_ELEMS;     // layer-1 outputs, 64 MB

  // zero the epoch flag dwords (dead hidden region of d_out, below hidden[2]
  // at 128 KB; rewritten by finals_kernel at the end)
  hipMemsetAsync(d_out, 0, FLAG_BYTES, stream);
  rnn_persist<<<96, 256, 0, stream>>>(x, h0, w_ih0, w_ihs, w_hhs, b_ihs, b_hhs,
                                      plane0, plane1, (float*)d_out);
  finals_kernel<<<128, 256, 0, stream>>>(plane0, plane1, (float*)d_out);
}

// Round 11
// 6445.184 us; speedup vs baseline: 1.5947x; 1.4950x over previous
//
#include <hip/hip_runtime.h>

// Persistent 3-layer tanh-RNN, B=32, S=1024, I=128, H=512.
// f16 split-2 (hi + lo*2^-12) x 3 MFMA products == fp32-class precision.
// 96 blocks = 3 layers x 16 j-groups(32 j) x 2 b-groups(16 b); weights live in
// VGPRs as MFMA B-frags for the whole kernel.
//
// R11 = R6 skeleton (best verified 6630us) + distributed epilogue under the
// PROVEN single-writer flag protocol. Protocol law from R0-R10: exactly one
// poll + one fence + one flag-writer per block + one release byte per step
// (R5/R8 coherent data loads, R9 double poll/fence, R9/R10 multi-writer flag
// dwords each cost 1-3us/step). Delta vs R6, epilogue only:
//   - all 4 waves publish P to LDS (conflict-free [wv][jt][r][lane], R10-
//     verified 0 conflicts); wave w reduces+tanh+stores rows r=w only
//     (2 tanh + 2 sc1 stores, was 8+16 serial on wave 0);
//   - each wave drains its own stores (parallel vmcnt(0)) -> ONE extra
//     barrier -> wave 0 lane 0 writes the SINGLE release byte (R6's exact
//     flag address/scheme). Drain+barrier+single-release keeps the
//     happens-before chain: peer stores are at the coherence point before
//     the barrier, flag follows it.
// Poll, fence, loads, MFMA, flag layout, memset: byte-identical to R6.
// All polls timeout-bounded (degrade, never hang).

typedef _Float16 half8 __attribute__((ext_vector_type(8)));
typedef float f32x4 __attribute__((ext_vector_type(4)));
typedef unsigned int uint32;
typedef unsigned short ushort16;

#define SCOPE_AGENT __HIP_MEMORY_SCOPE_AGENT
#define PLANE_ELEMS (32 * 1024 * 512)
#define FLAG_BYTES (6 * 16 * 1024)  // [c=(L,bg)][jg][t] bytes = 96 KB (dead hidden region of d_out)

__device__ __forceinline__ half8 h8(uint32 a, uint32 b, uint32 c, uint32 d) {
  union { uint32 u[4]; half8 h; } x;
  x.u[0] = a; x.u[1] = b; x.u[2] = c; x.u[3] = d;
  return x.h;
}

// pair dword: low16 = hi-f16 bits, high16 = lo-f16 bits
__device__ __forceinline__ void unpack_pair8(uint4 a, uint4 b, half8& hi, half8& lo) {
  hi = h8((a.x & 0xFFFFu) | (a.y << 16),
          (a.z & 0xFFFFu) | (a.w << 16),
          (b.x & 0xFFFFu) | (b.y << 16),
          (b.z & 0xFFFFu) | (b.w << 16));
  lo = h8((a.x >> 16) | (a.y & 0xFFFF0000u),
          (a.z >> 16) | (a.w & 0xFFFF0000u),
          (b.x >> 16) | (b.y & 0xFFFF0000u),
          (b.z >> 16) | (b.w & 0xFFFF0000u));
}

__device__ __forceinline__ void split8f(const float* v, half8& hi, half8& lo) {
  union { _Float16 e[8]; half8 h; } H, L;
#pragma unroll
  for (int i = 0; i < 8; ++i) {
    _Float16 h = (_Float16)v[i];
    H.e[i] = h;
    L.e[i] = (_Float16)((v[i] - (float)h) * 4096.0f);  // exact residual, scaled into f16 normal range
  }
  hi = H.h; lo = L.h;
}

__device__ __forceinline__ uint32 pack_pair(float xx) {
  _Float16 h = (_Float16)xx;
  _Float16 l = (_Float16)((xx - (float)h) * 4096.0f);
  union { _Float16 f; ushort16 u; } ch, cl;
  ch.f = h; cl.f = l;
  return (uint32)ch.u | ((uint32)cl.u << 16);
}

__device__ __forceinline__ void frag_from_f32(const float* p, half8& hi, half8& lo) {
  float v[8];
  *(float4*)(v)     = *(const float4*)(p);
  *(float4*)(v + 4) = *(const float4*)(p + 4);
  split8f(v, hi, lo);
}

__device__ __forceinline__ void frag_from_pairs(const uint32* p, half8& hi, half8& lo) {
  uint4 a = *(const uint4*)p;
  uint4 b = *(const uint4*)(p + 4);
  unpack_pair8(a, b, hi, lo);
}

template <int L>
__device__ void run_layer(const float* __restrict__ x, const float* __restrict__ h0,
                          const float* __restrict__ w_ih0, const float* __restrict__ w_ihs,
                          const float* __restrict__ w_hhs, const float* __restrict__ b_ihs,
                          const float* __restrict__ b_hhs, uint32* __restrict__ plane0,
                          uint32* __restrict__ plane1, float* __restrict__ outp, int jg, int bg) {
  constexpr int NKT = (L == 0) ? 20 : 32;   // K-tiles of 32 (l0: 4 x-tiles + 16 rec; else 16 in + 16 rec)
  constexpr int KTN = NKT / 4;              // tiles per wave
  constexpr int RECKT = (L == 0) ? 4 : 16;  // first recurrent tile

  unsigned char* flagb = (unsigned char*)outp;  // [c][jg][t] producer-done bytes (dead hidden region)
  float* hidden = outp;
  float* out2 = outp + 3 * 32 * 512;

  const int tid = threadIdx.x;
  const int w = tid >> 6;
  const int lane = tid & 63;
  const int ln16 = lane & 15;
  const int kgrp = lane >> 4;               // frag k-group: k8 = kgrp*8
  const int j0 = jg * 32;
  const int jc0 = j0 + ln16;                // jtile-0 column for this lane
  const int jc1 = j0 + 16 + ln16;           // jtile-1 column
  const int bloc = bg * 16 + ln16;          // A-frag row (batch)
  const int ktb = w * KTN;
  const int c = L * 2 + bg;                 // own producer-group id

  __shared__ float red[4][2][4][64];        // [wv][jt][r][lane] — lane-stride-1, conflict-free
  __shared__ int s_abort;
  if (tid == 0) s_abort = 0;

  // ---- preload weights (step-invariant) into VGPRs as hi/lo B-frags ----
  half8 Bhi[2][KTN], Blo[2][KTN];
#pragma unroll
  for (int jt = 0; jt < 2; ++jt) {
    const int j = j0 + jt * 16 + ln16;
#pragma unroll
    for (int ktl = 0; ktl < KTN; ++ktl) {
      const int kt = ktb + ktl;
      const float* wp;
      if (L == 0) {
        if (kt < 4) wp = w_ih0 + j * 128 + kt * 32 + kgrp * 8;
        else        wp = w_hhs + j * 512 + (kt - 4) * 32 + kgrp * 8;
      } else {
        if (kt < 16) wp = w_ihs + (L - 1) * 512 * 512 + j * 512 + kt * 32 + kgrp * 8;
        else         wp = w_hhs + L * 512 * 512 + j * 512 + (kt - 16) * 32 + kgrp * 8;
      }
      frag_from_f32(wp, Bhi[jt][ktl], Blo[jt][ktl]);
    }
  }

  const float bias0 = b_ihs[L * 512 + jc0] + b_hhs[L * 512 + jc0];
  const float bias1 = b_ihs[L * 512 + jc1] + b_hhs[L * 512 + jc1];
  uint32* myplane = (L == 0) ? plane0 : plane1;  // L==2 never uses it
  __syncthreads();

  for (int t = 0; t < 1024; ++t) {
    // ---- fused readiness poll: wave 0; lanes 0-15 own-layer(t-1), lanes 16-31 upstream(t) ----
    // One byte per producer block, each producer's bytes on its OWN line range
    // (R6 scheme, byte-identical).
    if (w == 0) {
      const unsigned char* bp = nullptr;
      if (lane < 16) {
        if (t > 0) bp = flagb + (c * 16 + lane) * 1024 + (t - 1);
      } else if (lane < 32) {
        if (L > 0) bp = flagb + (((L - 1) * 2 + bg) * 16 + (lane - 16)) * 1024 + t;
      }
      int spins = 0;
      for (;;) {
        bool ready = true;
        if (bp) ready = (__hip_atomic_load(bp, __ATOMIC_RELAXED, SCOPE_AGENT) == (unsigned char)1);
        if (__ballot(ready) == ~0ull) break;
        if (++spins > 250000) { if (lane == 0) s_abort = 1; break; }  // bounded budget -> degrade, never hang
        if (spins > 64) __builtin_amdgcn_s_sleep(1);
      }
      __builtin_amdgcn_fence(__ATOMIC_ACQUIRE, "agent");  // invalidate stale cached lines
    }
    __syncthreads();
    if (s_abort) break;

    // ---- per-step source row pointers ----
    const float* recF = nullptr; const uint32* recP = nullptr;
    if (t == 0)      recF = h0 + (L * 32 + bloc) * 512;
    else if (L < 2)  recP = myplane + ((t - 1) * 32 + bloc) * 512;
    else             recF = out2 + (bloc * 1024 + (t - 1)) * 512;

    const float* inF = nullptr; const uint32* inP = nullptr;
    if (L == 0)      inF = x + (bloc * 1024 + t) * 128;
    else if (L == 1) inP = plane0 + (t * 32 + bloc) * 512;
    else             inP = plane1 + (t * 32 + bloc) * 512;

    f32x4 C0 = {0.f, 0.f, 0.f, 0.f}, C1 = C0, X0 = C0, X1 = C0;

#pragma unroll
    for (int ktl = 0; ktl < KTN; ++ktl) {
      const int kt = ktb + ktl;
      half8 Ahi, Alo;
      if (kt < RECKT) {  // input half
        const int k = kt * 32 + kgrp * 8;
        if (L == 0) frag_from_f32(inF + k, Ahi, Alo);
        else        frag_from_pairs(inP + k, Ahi, Alo);
      } else {           // recurrent half
        const int k = (kt - RECKT) * 32 + kgrp * 8;
        if (t == 0 || L == 2) frag_from_f32(recF + k, Ahi, Alo);
        else                  frag_from_pairs(recP + k, Ahi, Alo);
      }
      C0 = __builtin_amdgcn_mfma_f32_16x16x32_f16(Ahi, Bhi[0][ktl], C0, 0, 0, 0);
      C1 = __builtin_amdgcn_mfma_f32_16x16x32_f16(Ahi, Bhi[1][ktl], C1, 0, 0, 0);
      X0 = __builtin_amdgcn_mfma_f32_16x16x32_f16(Ahi, Blo[0][ktl], X0, 0, 0, 0);
      X1 = __builtin_amdgcn_mfma_f32_16x16x32_f16(Ahi, Blo[1][ktl], X1, 0, 0, 0);
      X0 = __builtin_amdgcn_mfma_f32_16x16x32_f16(Alo, Bhi[0][ktl], X0, 0, 0, 0);
      X1 = __builtin_amdgcn_mfma_f32_16x16x32_f16(Alo, Bhi[1][ktl], X1, 0, 0, 0);
    }

    f32x4 P0 = C0 + X0 * (1.0f / 4096.0f);
    f32x4 P1 = C1 + X1 * (1.0f / 4096.0f);

    // ---- all waves publish P (conflict-free layout) ----
#pragma unroll
    for (int r = 0; r < 4; ++r) {
      red[w][0][r][lane] = P0[r];
      red[w][1][r][lane] = P1[r];
    }
    __syncthreads();

    // ---- distributed epilogue: wave w reduces + stores rows r = w ----
    {
      float s0 = red[0][0][w][lane] + red[1][0][w][lane] + red[2][0][w][lane] + red[3][0][w][lane];
      float s1 = red[0][1][w][lane] + red[1][1][w][lane] + red[2][1][w][lane] + red[3][1][w][lane];
      const float y0 = tanhf(s0 + bias0);
      const float y1 = tanhf(s1 + bias1);
      const int b = bg * 16 + kgrp * 4 + w;  // C/D: col=lane&15, row=(lane>>4)*4+r, r==w
      if (L < 2) {
        __hip_atomic_store(&myplane[(t * 32 + b) * 512 + jc0], pack_pair(y0), __ATOMIC_RELAXED, SCOPE_AGENT);
        __hip_atomic_store(&myplane[(t * 32 + b) * 512 + jc1], pack_pair(y1), __ATOMIC_RELAXED, SCOPE_AGENT);
      } else {
        __hip_atomic_store(&out2[(b * 1024 + t) * 512 + jc0], y0, __ATOMIC_RELAXED, SCOPE_AGENT);
        __hip_atomic_store(&out2[(b * 1024 + t) * 512 + jc1], y1, __ATOMIC_RELAXED, SCOPE_AGENT);
        if (t == 1023) {
          hidden[2 * 32 * 512 + b * 512 + jc0] = y0;
          hidden[2 * 32 * 512 + b * 512 + jc1] = y1;
        }
      }
    }
    // each wave drains ITS stores to the coherence point (parallel drains)
    asm volatile("s_waitcnt vmcnt(0)" ::: "memory");
    __syncthreads();  // all waves' stores are globally visible past this point

    // SINGLE release byte per block (proven single-writer protocol)
    if (tid == 0)
      __hip_atomic_store(flagb + (c * 16 + jg) * 1024 + t,
                         (unsigned char)1, __ATOMIC_RELEASE, SCOPE_AGENT);
    // WAR on red: next step's publishes happen only after the next post-poll
    // barrier, which follows every wave's epilogue reads of red this step.
  }
}

__global__ __launch_bounds__(256) void rnn_persist(
    const float* __restrict__ x, const float* __restrict__ h0,
    const float* __restrict__ w_ih0, const float* __restrict__ w_ihs,
    const float* __restrict__ w_hhs, const float* __restrict__ b_ihs,
    const float* __restrict__ b_hhs, uint32* __restrict__ plane0,
    uint32* __restrict__ plane1, float* __restrict__ outp) {
  const int bid = blockIdx.x;
  const int l = bid >> 5;
  const int idx = bid & 31;
  const int jg = idx >> 1;
  const int bg = idx & 1;
  if (l == 0)      run_layer<0>(x, h0, w_ih0, w_ihs, w_hhs, b_ihs, b_hhs, plane0, plane1, outp, jg, bg);
  else if (l == 1) run_layer<1>(x, h0, w_ih0, w_ihs, w_hhs, b_ihs, b_hhs, plane0, plane1, outp, jg, bg);
  else             run_layer<2>(x, h0, w_ih0, w_ihs, w_hhs, b_ihs, b_hhs, plane0, plane1, outp, jg, bg);
}

// hidden[l][b][j] for l in {0,1} from the last pair-plane slot (exact-ish: hi + lo*2^-12)
__global__ __launch_bounds__(256) void finals_kernel(const uint32* __restrict__ plane0,
                                                     const uint32* __restrict__ plane1,
                                                     float* __restrict__ outp) {
  int i = blockIdx.x * 256 + threadIdx.x;
  if (i >= 2 * 32 * 512) return;
  int l = i >> 14;
  int r = i & 16383;  // b*512 + j
  const uint32* pl = l ? plane1 : plane0;
  uint32 p = pl[1023 * 32 * 512 + r];
  union { ushort16 u; _Float16 f; } h, lo;
  h.u = (ushort16)(p & 0xFFFFu);
  lo.u = (ushort16)(p >> 16);
  outp[i] = (float)h.f + (float)lo.f * (1.0f / 4096.0f);
}

extern "C" void kernel_launch(void* const* d_in, const int* in_sizes, int n_in,
                              void* d_out, int out_size, void* d_ws, size_t ws_size,
                              hipStream_t stream) {
  const float* x     = (const float*)d_in[0];
  const float* h0    = (const float*)d_in[1];
  const float* w_ih0 = (const float*)d_in[2];
  const float* w_ihs = (const float*)d_in[3];
  const float* w_hhs = (const float*)d_in[4];
  const float* b_ihs = (const float*)d_in[5];
  const float* b_hhs = (const float*)d_in[6];

  uint32* plane0 = (uint32*)d_ws;            // layer-0 outputs, (hi,lo) f16 pairs, 64 MB
  uint32* plane1 = plane0 + PLANE_ELEMS;     // layer-1 outputs, 64 MB

  // zero the per-producer flag bytes (dead hidden region of d_out, below
  // hidden[2] at 128 KB; rewritten by finals_kernel at the end)
  hipMemsetAsync(d_out, 0, FLAG_BYTES, stream);
  rnn_persist<<<96, 256, 0, stream>>>(x, h0, w_ih0, w_ihs, w_hhs, b_ihs, b_hhs,
                                      plane0, plane1, (float*)d_out);
  finals_kernel<<<128, 256, 0, stream>>>(plane0, plane1, (float*)d_out);
}

// Round 12
// 4939.256 us; speedup vs baseline: 2.0810x; 1.3049x over previous
//
#include <hip/hip_runtime.h>

// Persistent 3-layer tanh-RNN, B=32, S=1024, I=128, H=512.
// f16 split-2 (hi + lo*2^-12) x 3 MFMA products == fp32-class precision.
// 96 blocks = 3 layers x 16 j-groups(32 j) x 2 b-groups(16 b); weights live in
// VGPRs as MFMA B-frags for the whole kernel.
//
// R12 = R11 (best verified, 6445us: R6 skeleton + distributed epilogue under
// the single-writer flag protocol) + ONE delta: PREFETCH-ALL A-tiles.
// After the acquire fence every load misses to L3; R11 interleaves load and
// decode so the compiler may chain several L3 round-trips. Now all KTN tile
// loads (plain cached uint4 pairs -- NOT coherent atomics, that was R5/R8's
// proven mistake) are issued into registers first, then decoded+MFMA'd:
// one L3 latency exposure instead of up to KTN. This isolates R5's delta-2
// (prefetch) from its delta-1 (coherent loads) which alone explained R5's
// regression (replicated by R8).
// Protocol law (R0-R10): ONE poll + ONE fence + ONE flag-writer per block +
// ONE release byte per step. All polls timeout-bounded (degrade, never hang).

typedef _Float16 half8 __attribute__((ext_vector_type(8)));
typedef float f32x4 __attribute__((ext_vector_type(4)));
typedef unsigned int uint32;
typedef unsigned short ushort16;

#define SCOPE_AGENT __HIP_MEMORY_SCOPE_AGENT
#define PLANE_ELEMS (32 * 1024 * 512)
#define FLAG_BYTES (6 * 16 * 1024)  // [c=(L,bg)][jg][t] bytes = 96 KB (dead hidden region of d_out)

__device__ __forceinline__ half8 h8(uint32 a, uint32 b, uint32 c, uint32 d) {
  union { uint32 u[4]; half8 h; } x;
  x.u[0] = a; x.u[1] = b; x.u[2] = c; x.u[3] = d;
  return x.h;
}

// pair dword: low16 = hi-f16 bits, high16 = lo-f16 bits
__device__ __forceinline__ void unpack_pair8(uint4 a, uint4 b, half8& hi, half8& lo) {
  hi = h8((a.x & 0xFFFFu) | (a.y << 16),
          (a.z & 0xFFFFu) | (a.w << 16),
          (b.x & 0xFFFFu) | (b.y << 16),
          (b.z & 0xFFFFu) | (b.w << 16));
  lo = h8((a.x >> 16) | (a.y & 0xFFFF0000u),
          (a.z >> 16) | (a.w & 0xFFFF0000u),
          (b.x >> 16) | (b.y & 0xFFFF0000u),
          (b.z >> 16) | (b.w & 0xFFFF0000u));
}

__device__ __forceinline__ void split8f(const float* v, half8& hi, half8& lo) {
  union { _Float16 e[8]; half8 h; } H, L;
#pragma unroll
  for (int i = 0; i < 8; ++i) {
    _Float16 h = (_Float16)v[i];
    H.e[i] = h;
    L.e[i] = (_Float16)((v[i] - (float)h) * 4096.0f);  // exact residual, scaled into f16 normal range
  }
  hi = H.h; lo = L.h;
}

__device__ __forceinline__ uint32 pack_pair(float xx) {
  _Float16 h = (_Float16)xx;
  _Float16 l = (_Float16)((xx - (float)h) * 4096.0f);
  union { _Float16 f; ushort16 u; } ch, cl;
  ch.f = h; cl.f = l;
  return (uint32)ch.u | ((uint32)cl.u << 16);
}

__device__ __forceinline__ void frag_from_f32(const float* p, half8& hi, half8& lo) {
  float v[8];
  *(float4*)(v)     = *(const float4*)(p);
  *(float4*)(v + 4) = *(const float4*)(p + 4);
  split8f(v, hi, lo);
}

template <int L>
__device__ void run_layer(const float* __restrict__ x, const float* __restrict__ h0,
                          const float* __restrict__ w_ih0, const float* __restrict__ w_ihs,
                          const float* __restrict__ w_hhs, const float* __restrict__ b_ihs,
                          const float* __restrict__ b_hhs, uint32* __restrict__ plane0,
                          uint32* __restrict__ plane1, float* __restrict__ outp, int jg, int bg) {
  constexpr int NKT = (L == 0) ? 20 : 32;   // K-tiles of 32 (l0: 4 x-tiles + 16 rec; else 16 in + 16 rec)
  constexpr int KTN = NKT / 4;              // tiles per wave
  constexpr int RECKT = (L == 0) ? 4 : 16;  // first recurrent tile

  unsigned char* flagb = (unsigned char*)outp;  // [c][jg][t] producer-done bytes (dead hidden region)
  float* hidden = outp;
  float* out2 = outp + 3 * 32 * 512;

  const int tid = threadIdx.x;
  const int w = tid >> 6;
  const int lane = tid & 63;
  const int ln16 = lane & 15;
  const int kgrp = lane >> 4;               // frag k-group: k8 = kgrp*8
  const int j0 = jg * 32;
  const int jc0 = j0 + ln16;                // jtile-0 column for this lane
  const int jc1 = j0 + 16 + ln16;           // jtile-1 column
  const int bloc = bg * 16 + ln16;          // A-frag row (batch)
  const int ktb = w * KTN;
  const int c = L * 2 + bg;                 // own producer-group id

  __shared__ float red[4][2][4][64];        // [wv][jt][r][lane] — lane-stride-1, conflict-free
  __shared__ int s_abort;
  if (tid == 0) s_abort = 0;

  // ---- preload weights (step-invariant) into VGPRs as hi/lo B-frags ----
  half8 Bhi[2][KTN], Blo[2][KTN];
#pragma unroll
  for (int jt = 0; jt < 2; ++jt) {
    const int j = j0 + jt * 16 + ln16;
#pragma unroll
    for (int ktl = 0; ktl < KTN; ++ktl) {
      const int kt = ktb + ktl;
      const float* wp;
      if (L == 0) {
        if (kt < 4) wp = w_ih0 + j * 128 + kt * 32 + kgrp * 8;
        else        wp = w_hhs + j * 512 + (kt - 4) * 32 + kgrp * 8;
      } else {
        if (kt < 16) wp = w_ihs + (L - 1) * 512 * 512 + j * 512 + kt * 32 + kgrp * 8;
        else         wp = w_hhs + L * 512 * 512 + j * 512 + (kt - 16) * 32 + kgrp * 8;
      }
      frag_from_f32(wp, Bhi[jt][ktl], Blo[jt][ktl]);
    }
  }

  const float bias0 = b_ihs[L * 512 + jc0] + b_hhs[L * 512 + jc0];
  const float bias1 = b_ihs[L * 512 + jc1] + b_hhs[L * 512 + jc1];
  uint32* myplane = (L == 0) ? plane0 : plane1;  // L==2 never uses it
  __syncthreads();

  for (int t = 0; t < 1024; ++t) {
    // ---- fused readiness poll: wave 0; lanes 0-15 own-layer(t-1), lanes 16-31 upstream(t) ----
    if (w == 0) {
      const unsigned char* bp = nullptr;
      if (lane < 16) {
        if (t > 0) bp = flagb + (c * 16 + lane) * 1024 + (t - 1);
      } else if (lane < 32) {
        if (L > 0) bp = flagb + (((L - 1) * 2 + bg) * 16 + (lane - 16)) * 1024 + t;
      }
      int spins = 0;
      for (;;) {
        bool ready = true;
        if (bp) ready = (__hip_atomic_load(bp, __ATOMIC_RELAXED, SCOPE_AGENT) == (unsigned char)1);
        if (__ballot(ready) == ~0ull) break;
        if (++spins > 250000) { if (lane == 0) s_abort = 1; break; }  // bounded budget -> degrade, never hang
        if (spins > 64) __builtin_amdgcn_s_sleep(1);
      }
      __builtin_amdgcn_fence(__ATOMIC_ACQUIRE, "agent");  // invalidate stale cached lines
    }
    __syncthreads();
    if (s_abort) break;

    // ---- per-step source row pointers ----
    const float* recF = nullptr; const uint32* recP = nullptr;
    if (t == 0)      recF = h0 + (L * 32 + bloc) * 512;
    else if (L < 2)  recP = myplane + ((t - 1) * 32 + bloc) * 512;
    else             recF = out2 + (bloc * 1024 + (t - 1)) * 512;

    const float* inF = nullptr; const uint32* inP = nullptr;
    if (L == 0)      inF = x + (bloc * 1024 + t) * 128;
    else if (L == 1) inP = plane0 + (t * 32 + bloc) * 512;
    else             inP = plane1 + (t * 32 + bloc) * 512;

    // ---- issue ALL A-tile loads first (plain cached; one L3 exposure, not KTN) ----
    uint4 ra[KTN], rb[KTN];
#pragma unroll
    for (int ktl = 0; ktl < KTN; ++ktl) {
      const int kt = ktb + ktl;
      const char* p;
      if (kt < RECKT) {  // input half
        const int k = kt * 32 + kgrp * 8;
        p = (L == 0) ? (const char*)(inF + k) : (const char*)(inP + k);
      } else {           // recurrent half
        const int k = (kt - RECKT) * 32 + kgrp * 8;
        p = (t == 0) ? (const char*)(recF + k)
                     : (L == 2) ? (const char*)(recF + k) : (const char*)(recP + k);
      }
      ra[ktl] = *(const uint4*)p;
      rb[ktl] = *(const uint4*)(p + 16);
    }

    // ---- decode + MFMA ----
    f32x4 C0 = {0.f, 0.f, 0.f, 0.f}, C1 = C0, X0 = C0, X1 = C0;
#pragma unroll
    for (int ktl = 0; ktl < KTN; ++ktl) {
      const int kt = ktb + ktl;
      const bool isf32 = (kt < RECKT) ? (L == 0) : (t == 0 || L == 2);
      half8 Ahi, Alo;
      if (isf32) {
        float v[8];
        *(uint4*)(v)     = ra[ktl];
        *(uint4*)(v + 4) = rb[ktl];
        split8f(v, Ahi, Alo);
      } else {
        unpack_pair8(ra[ktl], rb[ktl], Ahi, Alo);
      }
      C0 = __builtin_amdgcn_mfma_f32_16x16x32_f16(Ahi, Bhi[0][ktl], C0, 0, 0, 0);
      C1 = __builtin_amdgcn_mfma_f32_16x16x32_f16(Ahi, Bhi[1][ktl], C1, 0, 0, 0);
      X0 = __builtin_amdgcn_mfma_f32_16x16x32_f16(Ahi, Blo[0][ktl], X0, 0, 0, 0);
      X1 = __builtin_amdgcn_mfma_f32_16x16x32_f16(Ahi, Blo[1][ktl], X1, 0, 0, 0);
      X0 = __builtin_amdgcn_mfma_f32_16x16x32_f16(Alo, Bhi[0][ktl], X0, 0, 0, 0);
      X1 = __builtin_amdgcn_mfma_f32_16x16x32_f16(Alo, Bhi[1][ktl], X1, 0, 0, 0);
    }

    f32x4 P0 = C0 + X0 * (1.0f / 4096.0f);
    f32x4 P1 = C1 + X1 * (1.0f / 4096.0f);

    // ---- all waves publish P (conflict-free layout) ----
#pragma unroll
    for (int r = 0; r < 4; ++r) {
      red[w][0][r][lane] = P0[r];
      red[w][1][r][lane] = P1[r];
    }
    __syncthreads();

    // ---- distributed epilogue: wave w reduces + stores rows r = w ----
    {
      float s0 = red[0][0][w][lane] + red[1][0][w][lane] + red[2][0][w][lane] + red[3][0][w][lane];
      float s1 = red[0][1][w][lane] + red[1][1][w][lane] + red[2][1][w][lane] + red[3][1][w][lane];
      const float y0 = tanhf(s0 + bias0);
      const float y1 = tanhf(s1 + bias1);
      const int b = bg * 16 + kgrp * 4 + w;  // C/D: col=lane&15, row=(lane>>4)*4+r, r==w
      if (L < 2) {
        __hip_atomic_store(&myplane[(t * 32 + b) * 512 + jc0], pack_pair(y0), __ATOMIC_RELAXED, SCOPE_AGENT);
        __hip_atomic_store(&myplane[(t * 32 + b) * 512 + jc1], pack_pair(y1), __ATOMIC_RELAXED, SCOPE_AGENT);
      } else {
        __hip_atomic_store(&out2[(b * 1024 + t) * 512 + jc0], y0, __ATOMIC_RELAXED, SCOPE_AGENT);
        __hip_atomic_store(&out2[(b * 1024 + t) * 512 + jc1], y1, __ATOMIC_RELAXED, SCOPE_AGENT);
        if (t == 1023) {
          hidden[2 * 32 * 512 + b * 512 + jc0] = y0;
          hidden[2 * 32 * 512 + b * 512 + jc1] = y1;
        }
      }
    }
    // each wave drains ITS stores to the coherence point (parallel drains)
    asm volatile("s_waitcnt vmcnt(0)" ::: "memory");
    __syncthreads();  // all waves' stores are globally visible past this point

    // SINGLE release byte per block (proven single-writer protocol)
    if (tid == 0)
      __hip_atomic_store(flagb + (c * 16 + jg) * 1024 + t,
                         (unsigned char)1, __ATOMIC_RELEASE, SCOPE_AGENT);
  }
}

__global__ __launch_bounds__(256) void rnn_persist(
    const float* __restrict__ x, const float* __restrict__ h0,
    const float* __restrict__ w_ih0, const float* __restrict__ w_ihs,
    const float* __restrict__ w_hhs, const float* __restrict__ b_ihs,
    const float* __restrict__ b_hhs, uint32* __restrict__ plane0,
    uint32* __restrict__ plane1, float* __restrict__ outp) {
  const int bid = blockIdx.x;
  const int l = bid >> 5;
  const int idx = bid & 31;
  const int jg = idx >> 1;
  const int bg = idx & 1;
  if (l == 0)      run_layer<0>(x, h0, w_ih0, w_ihs, w_hhs, b_ihs, b_hhs, plane0, plane1, outp, jg, bg);
  else if (l == 1) run_layer<1>(x, h0, w_ih0, w_ihs, w_hhs, b_ihs, b_hhs, plane0, plane1, outp, jg, bg);
  else             run_layer<2>(x, h0, w_ih0, w_ihs, w_hhs, b_ihs, b_hhs, plane0, plane1, outp, jg, bg);
}

// hidden[l][b][j] for l in {0,1} from the last pair-plane slot (exact-ish: hi + lo*2^-12)
__global__ __launch_bounds__(256) void finals_kernel(const uint32* __restrict__ plane0,
                                                     const uint32* __restrict__ plane1,
                                                     float* __restrict__ outp) {
  int i = blockIdx.x * 256 + threadIdx.x;
  if (i >= 2 * 32 * 512) return;
  int l = i >> 14;
  int r = i & 16383;  // b*512 + j
  const uint32* pl = l ? plane1 : plane0;
  uint32 p = pl[1023 * 32 * 512 + r];
  union { ushort16 u; _Float16 f; } h, lo;
  h.u = (ushort16)(p & 0xFFFFu);
  lo.u = (ushort16)(p >> 16);
  outp[i] = (float)h.f + (float)lo.f * (1.0f / 4096.0f);
}

extern "C" void kernel_launch(void* const* d_in, const int* in_sizes, int n_in,
                              void* d_out, int out_size, void* d_ws, size_t ws_size,
                              hipStream_t stream) {
  const float* x     = (const float*)d_in[0];
  const float* h0    = (const float*)d_in[1];
  const float* w_ih0 = (const float*)d_in[2];
  const float* w_ihs = (const float*)d_in[3];
  const float* w_hhs = (const float*)d_in[4];
  const float* b_ihs = (const float*)d_in[5];
  const float* b_hhs = (const float*)d_in[6];

  uint32* plane0 = (uint32*)d_ws;            // layer-0 outputs, (hi,lo) f16 pairs, 64 MB
  uint32* plane1 = plane0 + PLANE_ELEMS;     // layer-1 outputs, 64 MB

  // zero the per-producer flag bytes (dead hidden region of d_out, below
  // hidden[2] at 128 KB; rewritten by finals_kernel at the end)
  hipMemsetAsync(d_out, 0, FLAG_BYTES, stream);
  rnn_persist<<<96, 256, 0, stream>>>(x, h0, w_ih0, w_ihs, w_hhs, b_ihs, b_hhs,
                                      plane0, plane1, (float*)d_out);
  finals_kernel<<<128, 256, 0, stream>>>(plane0, plane1, (float*)d_out);
}